// Round 2
// baseline (917.494 us; speedup 1.0000x reference)
//
#include <hip/hip_runtime.h>

typedef __bf16 bf16;
typedef __bf16 bf16x8 __attribute__((ext_vector_type(8)));
typedef __bf16 bf16x4 __attribute__((ext_vector_type(4)));
typedef float  f32x4  __attribute__((ext_vector_type(4)));

#define SCALE 0.125f   // Dh^-0.5, exact in bf16

// ---------------------------------------------------------------- casts/prep
__global__ __launch_bounds__(256) void cast4_kernel(const float* __restrict__ src,
                                                    bf16* __restrict__ dst, int n4) {
  int i = blockIdx.x * 256 + threadIdx.x;
  if (i >= n4) return;
  float4 v = ((const float4*)src)[i];
  bf16x4 o = { (bf16)v.x, (bf16)v.y, (bf16)v.z, (bf16)v.w };
  *(bf16x4*)(dst + (size_t)i * 4) = o;
}

// Builds Wqkvt (2304x768) = [Wq|Wkv]^T in bf16, Wpt (768x768) = Wp^T, bias1 = bq|bkv
__global__ __launch_bounds__(256) void prep_weights(
    const float* __restrict__ Wq, const float* __restrict__ Wkv,
    const float* __restrict__ Wp, const float* __restrict__ bq,
    const float* __restrict__ bkv,
    bf16* __restrict__ Wqkvt, bf16* __restrict__ Wpt, float* __restrict__ bias1) {
  int idx = blockIdx.x * 256 + threadIdx.x;
  const int T1 = 2304 * 768, T2 = 768 * 768;
  if (idx < T1) {
    int c = idx / 768, j = idx - c * 768;
    float v = (c < 768) ? Wq[(size_t)j * 768 + c] : Wkv[(size_t)j * 1536 + (c - 768)];
    Wqkvt[idx] = (bf16)v;
  } else if (idx < T1 + T2) {
    int t2 = idx - T1;
    int c = t2 / 768, j = t2 - c * 768;
    Wpt[t2] = (bf16)Wp[(size_t)j * 768 + c];
  } else if (idx < T1 + T2 + 2304) {
    int c = idx - T1 - T2;
    bias1[c] = (c < 768) ? bq[c] : bkv[c - 768];
  }
}

// ---------------------------------------------------------------- GEMM (A MxK, Bt NxK, bf16, fp32 acc)
// 128x128 tile, 4 waves in 2x2, each wave 64x64 = 4x4 mfma_f32_16x16x32_bf16 tiles.
__global__ __launch_bounds__(256) void gemm_bt(
    const bf16* __restrict__ A, const bf16* __restrict__ Bt,
    const float* __restrict__ bias,
    bf16* __restrict__ Cb, float* __restrict__ Cf,
    int Mdim, int Ndim, int Kdim) {
  __shared__ alignas(16) bf16 As[128 * 32];
  __shared__ alignas(16) bf16 Bs[128 * 32];
  int tid = threadIdx.x;
  int lane = tid & 63, wave = tid >> 6;
  int wr = wave >> 1, wc = wave & 1;
  int bm = blockIdx.y * 128, bn = blockIdx.x * 128;
  int lr = lane & 15, quad = lane >> 4;
  f32x4 acc[4][4] = {};
  for (int kb = 0; kb < Kdim; kb += 32) {
    __syncthreads();
#pragma unroll
    for (int i = 0; i < 2; i++) {
      int c = tid + i * 256;          // 512 16B-chunks per tile
      int r = c >> 2, cc = (c & 3) * 8;
      *(int4*)(As + r * 32 + cc) = *(const int4*)(A + (size_t)(bm + r) * Kdim + kb + cc);
      *(int4*)(Bs + r * 32 + cc) = *(const int4*)(Bt + (size_t)(bn + r) * Kdim + kb + cc);
    }
    __syncthreads();
    bf16x8 af[4], bg[4];
#pragma unroll
    for (int mi = 0; mi < 4; mi++)
      af[mi] = *(const bf16x8*)(As + (wr * 64 + mi * 16 + lr) * 32 + quad * 8);
#pragma unroll
    for (int ni = 0; ni < 4; ni++)
      bg[ni] = *(const bf16x8*)(Bs + (wc * 64 + ni * 16 + lr) * 32 + quad * 8);
#pragma unroll
    for (int mi = 0; mi < 4; mi++)
#pragma unroll
      for (int ni = 0; ni < 4; ni++)
        acc[mi][ni] = __builtin_amdgcn_mfma_f32_16x16x32_bf16(af[mi], bg[ni], acc[mi][ni], 0, 0, 0);
  }
#pragma unroll
  for (int mi = 0; mi < 4; mi++)
#pragma unroll
    for (int ni = 0; ni < 4; ni++)
#pragma unroll
      for (int r = 0; r < 4; r++) {
        int row = bm + wr * 64 + mi * 16 + quad * 4 + r;
        int col = bn + wc * 64 + ni * 16 + lr;
        float v = acc[mi][ni][r] + bias[col];
        if (Cb) Cb[(size_t)row * Ndim + col] = (bf16)v;
        else    Cf[(size_t)row * Ndim + col] = v;
      }
}

// ---------------------------------------------------------------- sim branch partials
// One block per (b,n) pair. Produces m_sim, l_sim, unnormalized o_sim.
__global__ __launch_bounds__(256) void sim_attn(
    const bf16* __restrict__ kvsim,   // [CH*8][1536] chunk-local
    const bf16* __restrict__ qkv,     // [8192][2304]
    int bn0,
    float* __restrict__ msim, float* __restrict__ lsim, float* __restrict__ osim) {
  __shared__ float qS[768];
  __shared__ float kS[8][768];
  __shared__ float vS[8][768];
  __shared__ float logitS[12][8];
  __shared__ float wS[12][8];
  int t = threadIdx.x;
  int pair = blockIdx.x;
  int bn = bn0 + pair;
  if (t < 96) {
    bf16 tmp[8];
    *(int4*)tmp = *(const int4*)(qkv + (size_t)bn * 2304 + t * 8);
#pragma unroll
    for (int e = 0; e < 8; e++) qS[t * 8 + e] = (float)tmp[e];
  }
  for (int ch = t; ch < 1536; ch += 256) {     // 8 rows x 192 chunks of 8
    int m = ch / 192;
    int cc = (ch - m * 192) * 8;
    bf16 tmp[8];
    *(int4*)tmp = *(const int4*)(kvsim + (size_t)(pair * 8 + m) * 1536 + cc);
    float* dstb = (cc < 768) ? &kS[m][cc] : &vS[m][cc - 768];
#pragma unroll
    for (int e = 0; e < 8; e++) dstb[e] = (float)tmp[e];
  }
  __syncthreads();
  if (t < 96) {
    int hh = t >> 3, m = t & 7;
    float s = 0.f;
#pragma unroll
    for (int d = 0; d < 64; d++) s += qS[hh * 64 + d] * kS[m][hh * 64 + d];
    logitS[hh][m] = s * SCALE;
  }
  __syncthreads();
  if (t < 12) {
    float mx = logitS[t][0];
#pragma unroll
    for (int m = 1; m < 8; m++) mx = fmaxf(mx, logitS[t][m]);
    float l = 0.f;
#pragma unroll
    for (int m = 0; m < 8; m++) { float e = __expf(logitS[t][m] - mx); wS[t][m] = e; l += e; }
    msim[(size_t)bn * 12 + t] = mx;
    lsim[(size_t)bn * 12 + t] = l;
  }
  __syncthreads();
  for (int d = t; d < 768; d += 256) {
    int hh = d >> 6;
    float o = 0.f;
#pragma unroll
    for (int m = 0; m < 8; m++) o += wS[hh][m] * vS[m][d];
    osim[(size_t)bn * 768 + d] = o;
  }
}

// ---------------------------------------------------------------- self attention + merge
// One block (4 waves) per (b,h). K/V of whole head resident in LDS (~156KB).
__global__ __launch_bounds__(256) void self_attn(
    const bf16* __restrict__ qkv,
    const float* __restrict__ msim, const float* __restrict__ lsim,
    const float* __restrict__ osim,
    bf16* __restrict__ attn_out) {
  __shared__ alignas(16) bf16 Ks[512][72];    // K rows (j,d), padded
  __shared__ alignas(16) bf16 Vt[64][520];    // V^T (d,j), padded
  __shared__ alignas(16) bf16 Ps[16][520];    // P tile (qrow, j)
  __shared__ alignas(16) bf16 Qs[16][72];     // Q tile, pre-scaled
  __shared__ float mrowS[16], lrowS[16];
  __shared__ float red[4][16];
  int b = blockIdx.x / 12, h = blockIdx.x - b * 12;
  int rowbase = b * 512;
  int t = threadIdx.x, lane = t & 63, wv = t >> 6;
  int lr = lane & 15, quad = lane >> 4;

  for (int ci = t; ci < 4096; ci += 256) {    // 512 rows x 8 chunks
    int j = ci >> 3, off = (ci & 7) * 8;
    const bf16* src = qkv + (size_t)(rowbase + j) * 2304 + 768 + h * 64 + off;
    *(int4*)(&Ks[j][off]) = *(const int4*)src;
    bf16 tmp[8];
    *(int4*)tmp = *(const int4*)(src + 768);  // v part
#pragma unroll
    for (int e = 0; e < 8; e++) Vt[off + e][j] = tmp[e];
  }
  __syncthreads();

  for (int qt = 0; qt < 32; qt++) {
    if (t < 128) {
      int j = t >> 3, off = (t & 7) * 8;
      bf16 tmp[8];
      *(int4*)tmp = *(const int4*)(qkv + (size_t)(rowbase + qt * 16 + j) * 2304 + h * 64 + off);
#pragma unroll
      for (int e = 0; e < 8; e++) Qs[j][off + e] = (bf16)((float)tmp[e] * SCALE);
    }
    __syncthreads();

    // S = Q K^T : wave wv owns columns wv*128 .. +128
    f32x4 sacc[8] = {};
    bf16x8 aq0 = *(const bf16x8*)(&Qs[lr][quad * 8]);
    bf16x8 aq1 = *(const bf16x8*)(&Qs[lr][32 + quad * 8]);
#pragma unroll
    for (int ni = 0; ni < 8; ni++) {
      int jb = wv * 128 + ni * 16 + lr;
      bf16x8 bk0 = *(const bf16x8*)(&Ks[jb][quad * 8]);
      bf16x8 bk1 = *(const bf16x8*)(&Ks[jb][32 + quad * 8]);
      sacc[ni] = __builtin_amdgcn_mfma_f32_16x16x32_bf16(aq0, bk0, sacc[ni], 0, 0, 0);
      sacc[ni] = __builtin_amdgcn_mfma_f32_16x16x32_bf16(aq1, bk1, sacc[ni], 0, 0, 0);
    }
    // row max (C-layout: row = quad*4+r, col = lane&15)
    float m4[4];
#pragma unroll
    for (int r = 0; r < 4; r++) {
      float v = sacc[0][r];
#pragma unroll
      for (int ni = 1; ni < 8; ni++) v = fmaxf(v, sacc[ni][r]);
      m4[r] = v;
    }
#pragma unroll
    for (int s = 1; s < 16; s <<= 1)
#pragma unroll
      for (int r = 0; r < 4; r++) m4[r] = fmaxf(m4[r], __shfl_xor(m4[r], s, 64));
    if (lr == 0)
#pragma unroll
      for (int r = 0; r < 4; r++) red[wv][quad * 4 + r] = m4[r];
    __syncthreads();
    if (t < 16) mrowS[t] = fmaxf(fmaxf(red[0][t], red[1][t]), fmaxf(red[2][t], red[3][t]));
    __syncthreads();

    float s4[4] = {0.f, 0.f, 0.f, 0.f};
#pragma unroll
    for (int ni = 0; ni < 8; ni++)
#pragma unroll
      for (int r = 0; r < 4; r++) {
        float p = __expf(sacc[ni][r] - mrowS[quad * 4 + r]);
        s4[r] += p;
        Ps[quad * 4 + r][wv * 128 + ni * 16 + lr] = (bf16)p;
      }
#pragma unroll
    for (int s = 1; s < 16; s <<= 1)
#pragma unroll
      for (int r = 0; r < 4; r++) s4[r] += __shfl_xor(s4[r], s, 64);
    if (lr == 0)
#pragma unroll
      for (int r = 0; r < 4; r++) red[wv][quad * 4 + r] = s4[r];
    __syncthreads();
    if (t < 16) lrowS[t] = red[0][t] + red[1][t] + red[2][t] + red[3][t];
    __syncthreads();

    // O = P V : wave wv owns output cols wv*16 .. +16
    f32x4 oacc = {0.f, 0.f, 0.f, 0.f};
#pragma unroll
    for (int kb = 0; kb < 16; kb++) {
      bf16x8 ap = *(const bf16x8*)(&Ps[lr][kb * 32 + quad * 8]);
      bf16x8 bv = *(const bf16x8*)(&Vt[wv * 16 + lr][kb * 32 + quad * 8]);
      oacc = __builtin_amdgcn_mfma_f32_16x16x32_bf16(ap, bv, oacc, 0, 0, 0);
    }
    // merge with sim-branch partials, write attn_out
#pragma unroll
    for (int r = 0; r < 4; r++) {
      int rowl = quad * 4 + r;
      int bnI = rowbase + qt * 16 + rowl;
      int d = wv * 16 + lr;
      float mself = mrowS[rowl], lself = lrowS[rowl];
      float ms = msim[(size_t)bnI * 12 + h], ls = lsim[(size_t)bnI * 12 + h];
      float mt = fmaxf(mself, ms);
      float ea = __expf(mself - mt), eb = __expf(ms - mt);
      float denom = lself * ea + ls * eb;
      float val = (oacc[r] * ea + osim[(size_t)bnI * 768 + h * 64 + d] * eb) / denom;
      attn_out[(size_t)bnI * 768 + h * 64 + d] = (bf16)val;
    }
    __syncthreads();
  }
}

// ---------------------------------------------------------------- launch
extern "C" void kernel_launch(void* const* d_in, const int* in_sizes, int n_in,
                              void* d_out, int out_size, void* d_ws, size_t ws_size,
                              hipStream_t stream) {
  const float* x   = (const float*)d_in[0];
  const float* sim = (const float*)d_in[1];
  const float* Wq  = (const float*)d_in[2];
  const float* bq  = (const float*)d_in[3];
  const float* Wkv = (const float*)d_in[4];
  const float* bkv = (const float*)d_in[5];
  const float* Wp  = (const float*)d_in[6];
  const float* bp  = (const float*)d_in[7];
  float* out = (float*)d_out;

  char* ws = (char*)d_ws;
  size_t off = 0;
  auto carve = [&](size_t bytes) -> char* {
    char* p = ws + off;
    off = (off + bytes + 255) & ~(size_t)255;
    return p;
  };
  bf16*  xb    = (bf16*) carve((size_t)8192 * 768 * 2);
  bf16*  Wqkvt = (bf16*) carve((size_t)2304 * 768 * 2);
  bf16*  Wpt   = (bf16*) carve((size_t)768 * 768 * 2);
  float* bias1 = (float*)carve(2304 * 4);
  bf16*  qkv   = (bf16*) carve((size_t)8192 * 2304 * 2);
  float* msim  = (float*)carve((size_t)8192 * 12 * 4);
  float* lsim  = (float*)carve((size_t)8192 * 12 * 4);
  float* osim  = (float*)carve((size_t)8192 * 768 * 4);
  bf16*  attn  = (bf16*) carve((size_t)8192 * 768 * 2);
  size_t rem = (ws_size > off) ? ws_size - off : 0;
  int CH = 1024;                                   // (b,n) pairs per chunk (8192 total)
  while (CH > 16 && (size_t)CH * 36864 > rem) CH >>= 1;
  bf16* simb  = (bf16*)carve((size_t)CH * 8 * 768 * 2);
  bf16* kvsim = (bf16*)carve((size_t)CH * 8 * 1536 * 2);

  cast4_kernel<<<6144, 256, 0, stream>>>(x, xb, 8192 * 768 / 4);
  prep_weights<<<(2304 * 768 + 768 * 768 + 2304 + 255) / 256, 256, 0, stream>>>(
      Wq, Wkv, Wp, bq, bkv, Wqkvt, Wpt, bias1);
  // qkv = x @ [Wq|Wkv] + [bq|bkv]
  gemm_bt<<<dim3(18, 64), 256, 0, stream>>>(xb, Wqkvt, bias1, qkv, nullptr, 8192, 2304, 768);

  int nch = 8192 / CH;   // FIX (R1 bug): B*N = 8192 (b,n) pairs, not 1024 —
                         // previously 7/8 of rows merged against poison sim partials.
  for (int c = 0; c < nch; c++) {
    int pairs0 = c * CH;
    cast4_kernel<<<CH * 6, 256, 0, stream>>>(sim + (size_t)pairs0 * 8 * 768, simb, CH * 8 * 768 / 4);
    // kv_sim chunk = sim_chunk @ Wkv + bkv   (Bt = rows 768.. of Wqkvt)
    gemm_bt<<<dim3(12, CH * 8 / 128), 256, 0, stream>>>(
        simb, Wqkvt + (size_t)768 * 768, bkv, kvsim, nullptr, CH * 8, 1536, 768);
    sim_attn<<<CH, 256, 0, stream>>>(kvsim, qkv, pairs0, msim, lsim, osim);
  }
  self_attn<<<192, 256, 0, stream>>>(qkv, msim, lsim, osim, attn);
  // out = attn @ Wp + bp (fp32 out)
  gemm_bt<<<dim3(6, 64), 256, 0, stream>>>(attn, Wpt, bp, nullptr, out, 8192, 768, 768);
}

// Round 3
// 857.109 us; speedup vs baseline: 1.0705x; 1.0705x over previous
//
#include <hip/hip_runtime.h>

typedef __bf16 bf16;
typedef __bf16 bf16x8 __attribute__((ext_vector_type(8)));
typedef __bf16 bf16x4 __attribute__((ext_vector_type(4)));
typedef float  f32x4  __attribute__((ext_vector_type(4)));

#define SCALE 0.125f   // Dh^-0.5, exact in bf16

__device__ __forceinline__ void gl_lds16(const bf16* g, bf16* l) {
  __builtin_amdgcn_global_load_lds(
      (const __attribute__((address_space(1))) void*)g,
      (__attribute__((address_space(3))) void*)l, 16, 0, 0);
}

// ---------------------------------------------------------------- casts/prep
__global__ __launch_bounds__(256) void cast4_kernel(const float* __restrict__ src,
                                                    bf16* __restrict__ dst, int n4) {
  int i = blockIdx.x * 256 + threadIdx.x;
  if (i >= n4) return;
  float4 v = ((const float4*)src)[i];
  bf16x4 o = { (bf16)v.x, (bf16)v.y, (bf16)v.z, (bf16)v.w };
  *(bf16x4*)(dst + (size_t)i * 4) = o;
}

// Builds Wqkvt (2304x768) = [Wq|Wkv]^T in bf16, Wpt (768x768) = Wp^T, bias1 = bq|bkv
__global__ __launch_bounds__(256) void prep_weights(
    const float* __restrict__ Wq, const float* __restrict__ Wkv,
    const float* __restrict__ Wp, const float* __restrict__ bq,
    const float* __restrict__ bkv,
    bf16* __restrict__ Wqkvt, bf16* __restrict__ Wpt, float* __restrict__ bias1) {
  int idx = blockIdx.x * 256 + threadIdx.x;
  const int T1 = 2304 * 768, T2 = 768 * 768;
  if (idx < T1) {
    int c = idx / 768, j = idx - c * 768;
    float v = (c < 768) ? Wq[(size_t)j * 768 + c] : Wkv[(size_t)j * 1536 + (c - 768)];
    Wqkvt[idx] = (bf16)v;
  } else if (idx < T1 + T2) {
    int t2 = idx - T1;
    int c = t2 / 768, j = t2 - c * 768;
    Wpt[t2] = (bf16)Wp[(size_t)j * 768 + c];
  } else if (idx < T1 + T2 + 2304) {
    int c = idx - T1 - T2;
    bias1[c] = (c < 768) ? bq[c] : bkv[c - 768];
  }
}

// ---------------------------------------------------------------- GEMM (A MxK, Bt NxK, bf16, fp32 acc)
// 128x128 tile, 4 waves in 2x2, each wave 64x64 = 4x4 mfma_f32_16x16x32_bf16 tiles.
// Staging via global_load_lds width=16 (async DMA, wave-uniform LDS base + lane*16).
__global__ __launch_bounds__(256) void gemm_bt(
    const bf16* __restrict__ A, const bf16* __restrict__ Bt,
    const float* __restrict__ bias,
    bf16* __restrict__ Cb, float* __restrict__ Cf,
    int Mdim, int Ndim, int Kdim) {
  __shared__ alignas(16) bf16 As[128 * 32];
  __shared__ alignas(16) bf16 Bs[128 * 32];
  int tid = threadIdx.x;
  int lane = tid & 63, wave = tid >> 6;
  int wr = wave >> 1, wc = wave & 1;
  int bm = blockIdx.y * 128, bn = blockIdx.x * 128;
  int lr = lane & 15, quad = lane >> 4;
  f32x4 acc[4][4] = {};
  for (int kb = 0; kb < Kdim; kb += 32) {
    __syncthreads();
#pragma unroll
    for (int i = 0; i < 2; i++) {
      int c = tid + i * 256;          // 512 16B-chunks per tile; LDS byte = c*16
      int r = c >> 2, cc = (c & 3) * 8;
      bf16* ldsbase_a = As + ((size_t)i * 256 + wave * 64) * 8;  // wave-uniform
      bf16* ldsbase_b = Bs + ((size_t)i * 256 + wave * 64) * 8;
      gl_lds16(A + (size_t)(bm + r) * Kdim + kb + cc, ldsbase_a);
      gl_lds16(Bt + (size_t)(bn + r) * Kdim + kb + cc, ldsbase_b);
    }
    __syncthreads();
    bf16x8 af[4], bg[4];
#pragma unroll
    for (int mi = 0; mi < 4; mi++)
      af[mi] = *(const bf16x8*)(As + (wr * 64 + mi * 16 + lr) * 32 + quad * 8);
#pragma unroll
    for (int ni = 0; ni < 4; ni++)
      bg[ni] = *(const bf16x8*)(Bs + (wc * 64 + ni * 16 + lr) * 32 + quad * 8);
#pragma unroll
    for (int mi = 0; mi < 4; mi++)
#pragma unroll
      for (int ni = 0; ni < 4; ni++)
        acc[mi][ni] = __builtin_amdgcn_mfma_f32_16x16x32_bf16(af[mi], bg[ni], acc[mi][ni], 0, 0, 0);
  }
#pragma unroll
  for (int mi = 0; mi < 4; mi++)
#pragma unroll
    for (int ni = 0; ni < 4; ni++)
#pragma unroll
      for (int r = 0; r < 4; r++) {
        int row = bm + wr * 64 + mi * 16 + quad * 4 + r;
        int col = bn + wc * 64 + ni * 16 + lr;
        float v = acc[mi][ni][r] + bias[col];
        if (Cb) Cb[(size_t)row * Ndim + col] = (bf16)v;
        else    Cf[(size_t)row * Ndim + col] = v;
      }
}

// ---------------------------------------------------------------- sim branch partials
// One block per (b,n) pair. Produces m_sim, l_sim, unnormalized o_sim.
__global__ __launch_bounds__(256) void sim_attn(
    const bf16* __restrict__ kvsim,   // [CH*8][1536] chunk-local
    const bf16* __restrict__ qkv,     // [8192][2304]
    int bn0,
    float* __restrict__ msim, float* __restrict__ lsim, float* __restrict__ osim) {
  __shared__ float qS[768];
  __shared__ float kS[8][768];
  __shared__ float vS[8][768];
  __shared__ float logitS[12][8];
  __shared__ float wS[12][8];
  int t = threadIdx.x;
  int pair = blockIdx.x;
  int bn = bn0 + pair;
  if (t < 96) {
    bf16 tmp[8];
    *(int4*)tmp = *(const int4*)(qkv + (size_t)bn * 2304 + t * 8);
#pragma unroll
    for (int e = 0; e < 8; e++) qS[t * 8 + e] = (float)tmp[e];
  }
  for (int ch = t; ch < 1536; ch += 256) {     // 8 rows x 192 chunks of 8
    int m = ch / 192;
    int cc = (ch - m * 192) * 8;
    bf16 tmp[8];
    *(int4*)tmp = *(const int4*)(kvsim + (size_t)(pair * 8 + m) * 1536 + cc);
    float* dstb = (cc < 768) ? &kS[m][cc] : &vS[m][cc - 768];
#pragma unroll
    for (int e = 0; e < 8; e++) dstb[e] = (float)tmp[e];
  }
  __syncthreads();
  if (t < 96) {
    int hh = t >> 3, m = t & 7;
    float s = 0.f;
#pragma unroll
    for (int d = 0; d < 64; d++) s += qS[hh * 64 + d] * kS[m][hh * 64 + d];
    logitS[hh][m] = s * SCALE;
  }
  __syncthreads();
  if (t < 12) {
    float mx = logitS[t][0];
#pragma unroll
    for (int m = 1; m < 8; m++) mx = fmaxf(mx, logitS[t][m]);
    float l = 0.f;
#pragma unroll
    for (int m = 0; m < 8; m++) { float e = __expf(logitS[t][m] - mx); wS[t][m] = e; l += e; }
    msim[(size_t)bn * 12 + t] = mx;
    lsim[(size_t)bn * 12 + t] = l;
  }
  __syncthreads();
  for (int d = t; d < 768; d += 256) {
    int hh = d >> 6;
    float o = 0.f;
#pragma unroll
    for (int m = 0; m < 8; m++) o += wS[hh][m] * vS[m][d];
    osim[(size_t)bn * 768 + d] = o;
  }
}

// ---------------------------------------------------------------- self attention + merge (flash-style)
// Grid: b(16) x h(12) x qchunk(8 of 64 rows) = 1536 blocks. 4 waves; wave wv owns
// q-rows qc*64 + wv*16.. (online softmax state in registers, wave-private P strip).
// LDS 52 KB -> 3 blocks/CU (12 waves/CU) vs old 156 KB -> 1 block/CU.
__global__ __launch_bounds__(256) void self_attn(
    const bf16* __restrict__ qkv,
    const float* __restrict__ msim, const float* __restrict__ lsim,
    const float* __restrict__ osim,
    bf16* __restrict__ attn_out) {
  __shared__ alignas(16) bf16 Ks[128][72];     // K tile rows (j,d)
  __shared__ alignas(16) bf16 Vt[64][136];     // V^T tile (d, j)
  __shared__ alignas(16) bf16 Ps[4][16][136];  // per-wave P strip (qrow, j)
  int bid = blockIdx.x;
  int qc = bid & 7;
  int h  = (bid >> 3) % 12;
  int b  = bid / 96;
  int rowbase = b * 512;
  int q0 = qc * 64;
  int t = threadIdx.x, lane = t & 63, wv = t >> 6;
  int lr = lane & 15, quad = lane >> 4;

  // Q A-fragments straight from global (m = lr), unscaled; SCALE folded into S.
  const bf16* qrow = qkv + (size_t)(rowbase + q0 + wv * 16 + lr) * 2304 + h * 64;
  bf16x8 aq0 = *(const bf16x8*)(qrow + quad * 8);
  bf16x8 aq1 = *(const bf16x8*)(qrow + 32 + quad * 8);

  f32x4 oacc[4] = {};                 // 16 q-rows x 64 d (C-layout per ni)
  float mrow[4], lrow[4];
#pragma unroll
  for (int r = 0; r < 4; r++) { mrow[r] = -1e30f; lrow[r] = 0.f; }

  for (int kt = 0; kt < 4; kt++) {
    int jb = kt * 128;
    __syncthreads();                  // prev tile's readers done
    for (int ci = t; ci < 1024; ci += 256) {        // K: 128 rows x 8 int4, off-fast
      int j = ci >> 3, off = (ci & 7) * 8;
      *(int4*)(&Ks[j][off]) =
          *(const int4*)(qkv + (size_t)(rowbase + jb + j) * 2304 + 768 + h * 64 + off);
    }
    for (int ci = t; ci < 512; ci += 256) {         // V^T: j-pair packed b32 writes
      int jp = ci >> 3, off = (ci & 7) * 8;
      const bf16* v0 = qkv + (size_t)(rowbase + jb + jp * 2) * 2304 + 1536 + h * 64 + off;
      bf16 ta[8], tb[8];
      *(int4*)ta = *(const int4*)v0;
      *(int4*)tb = *(const int4*)(v0 + 2304);
#pragma unroll
      for (int e = 0; e < 8; e++) {
        bf16 pr[2] = { ta[e], tb[e] };
        *(unsigned*)(&Vt[off + e][jp * 2]) = *(unsigned*)pr;
      }
    }
    __syncthreads();

    // S strip = Q(16x64) K^T(128x64): 16 rows x 128 cols per wave
    f32x4 sacc[8] = {};
#pragma unroll
    for (int ni = 0; ni < 8; ni++) {
      int jj = ni * 16 + lr;
      bf16x8 bk0 = *(const bf16x8*)(&Ks[jj][quad * 8]);
      bf16x8 bk1 = *(const bf16x8*)(&Ks[jj][32 + quad * 8]);
      sacc[ni] = __builtin_amdgcn_mfma_f32_16x16x32_bf16(aq0, bk0, sacc[ni], 0, 0, 0);
      sacc[ni] = __builtin_amdgcn_mfma_f32_16x16x32_bf16(aq1, bk1, sacc[ni], 0, 0, 0);
    }
    // online softmax update; C-layout row = quad*4+r, col = ni*16+lr
    float tm[4];
#pragma unroll
    for (int r = 0; r < 4; r++) {
      float v = sacc[0][r];
#pragma unroll
      for (int ni = 1; ni < 8; ni++) v = fmaxf(v, sacc[ni][r]);
      tm[r] = v;
    }
#pragma unroll
    for (int s = 1; s < 16; s <<= 1)
#pragma unroll
      for (int r = 0; r < 4; r++) tm[r] = fmaxf(tm[r], __shfl_xor(tm[r], s, 64));
    float alpha[4], s4[4];
#pragma unroll
    for (int r = 0; r < 4; r++) {
      float mnew = fmaxf(mrow[r], tm[r] * SCALE);
      alpha[r] = __expf(mrow[r] - mnew);
      mrow[r] = mnew;
      s4[r] = 0.f;
    }
#pragma unroll
    for (int ni = 0; ni < 8; ni++)
#pragma unroll
      for (int r = 0; r < 4; r++) {
        float p = __expf(sacc[ni][r] * SCALE - mrow[r]);
        s4[r] += p;
        Ps[wv][quad * 4 + r][ni * 16 + lr] = (bf16)p;
      }
#pragma unroll
    for (int s = 1; s < 16; s <<= 1)
#pragma unroll
      for (int r = 0; r < 4; r++) s4[r] += __shfl_xor(s4[r], s, 64);
#pragma unroll
    for (int r = 0; r < 4; r++) lrow[r] = lrow[r] * alpha[r] + s4[r];
#pragma unroll
    for (int ni = 0; ni < 4; ni++)
#pragma unroll
      for (int r = 0; r < 4; r++) oacc[ni][r] *= alpha[r];

    // O strip += P(16x128) V(128x64)  (wave-private Ps: no barrier needed;
    // LDS ops from one wave execute in order)
#pragma unroll
    for (int kb = 0; kb < 4; kb++) {
      bf16x8 ap = *(const bf16x8*)(&Ps[wv][lr][kb * 32 + quad * 8]);
#pragma unroll
      for (int ni = 0; ni < 4; ni++) {
        bf16x8 bv = *(const bf16x8*)(&Vt[ni * 16 + lr][kb * 32 + quad * 8]);
        oacc[ni] = __builtin_amdgcn_mfma_f32_16x16x32_bf16(ap, bv, oacc[ni], 0, 0, 0);
      }
    }
  }

  // merge with sim-branch partials, normalize, write
#pragma unroll
  for (int r = 0; r < 4; r++) {
    int bnI = rowbase + q0 + wv * 16 + quad * 4 + r;
    float ms = msim[(size_t)bnI * 12 + h], ls = lsim[(size_t)bnI * 12 + h];
    float mt = fmaxf(mrow[r], ms);
    float ea = __expf(mrow[r] - mt), eb = __expf(ms - mt);
    float inv = 1.f / (lrow[r] * ea + ls * eb);
#pragma unroll
    for (int ni = 0; ni < 4; ni++) {
      int d = ni * 16 + lr;
      float val = (oacc[ni][r] * ea + osim[(size_t)bnI * 768 + h * 64 + d] * eb) * inv;
      attn_out[(size_t)bnI * 768 + h * 64 + d] = (bf16)val;
    }
  }
}

// ---------------------------------------------------------------- launch
extern "C" void kernel_launch(void* const* d_in, const int* in_sizes, int n_in,
                              void* d_out, int out_size, void* d_ws, size_t ws_size,
                              hipStream_t stream) {
  const float* x   = (const float*)d_in[0];
  const float* sim = (const float*)d_in[1];
  const float* Wq  = (const float*)d_in[2];
  const float* bq  = (const float*)d_in[3];
  const float* Wkv = (const float*)d_in[4];
  const float* bkv = (const float*)d_in[5];
  const float* Wp  = (const float*)d_in[6];
  const float* bp  = (const float*)d_in[7];
  float* out = (float*)d_out;

  char* ws = (char*)d_ws;
  size_t off = 0;
  auto carve = [&](size_t bytes) -> char* {
    char* p = ws + off;
    off = (off + bytes + 255) & ~(size_t)255;
    return p;
  };
  bf16*  xb    = (bf16*) carve((size_t)8192 * 768 * 2);
  bf16*  Wqkvt = (bf16*) carve((size_t)2304 * 768 * 2);
  bf16*  Wpt   = (bf16*) carve((size_t)768 * 768 * 2);
  float* bias1 = (float*)carve(2304 * 4);
  bf16*  qkv   = (bf16*) carve((size_t)8192 * 2304 * 2);
  float* msim  = (float*)carve((size_t)8192 * 12 * 4);
  float* lsim  = (float*)carve((size_t)8192 * 12 * 4);
  float* osim  = (float*)carve((size_t)8192 * 768 * 4);
  bf16*  attn  = (bf16*) carve((size_t)8192 * 768 * 2);
  size_t rem = (ws_size > off) ? ws_size - off : 0;
  int CH = 1024;                                   // (b,n) pairs per chunk (8192 total)
  while (CH > 16 && (size_t)CH * 36864 > rem) CH >>= 1;
  bf16* simb  = (bf16*)carve((size_t)CH * 8 * 768 * 2);
  bf16* kvsim = (bf16*)carve((size_t)CH * 8 * 1536 * 2);

  cast4_kernel<<<6144, 256, 0, stream>>>(x, xb, 8192 * 768 / 4);
  prep_weights<<<(2304 * 768 + 768 * 768 + 2304 + 255) / 256, 256, 0, stream>>>(
      Wq, Wkv, Wp, bq, bkv, Wqkvt, Wpt, bias1);
  // qkv = x @ [Wq|Wkv] + [bq|bkv]
  gemm_bt<<<dim3(18, 64), 256, 0, stream>>>(xb, Wqkvt, bias1, qkv, nullptr, 8192, 2304, 768);

  int nch = 8192 / CH;
  for (int c = 0; c < nch; c++) {
    int pairs0 = c * CH;
    cast4_kernel<<<CH * 6, 256, 0, stream>>>(sim + (size_t)pairs0 * 8 * 768, simb, CH * 8 * 768 / 4);
    // kv_sim chunk = sim_chunk @ Wkv + bkv   (Bt = rows 768.. of Wqkvt)
    gemm_bt<<<dim3(12, CH * 8 / 128), 256, 0, stream>>>(
        simb, Wqkvt + (size_t)768 * 768, bkv, kvsim, nullptr, CH * 8, 1536, 768);
    sim_attn<<<CH, 256, 0, stream>>>(kvsim, qkv, pairs0, msim, lsim, osim);
  }
  self_attn<<<1536, 256, 0, stream>>>(qkv, msim, lsim, osim, attn);
  // out = attn @ Wp + bp (fp32 out)
  gemm_bt<<<dim3(6, 64), 256, 0, stream>>>(attn, Wpt, bp, nullptr, out, 8192, 768, 768);
}